// Round 8
// baseline (517.036 us; speedup 1.0000x reference)
//
#include <hip/hip_runtime.h>
#include <hip/hip_bf16.h>

typedef __attribute__((ext_vector_type(8))) short bf16x8;
typedef __attribute__((ext_vector_type(4))) float f32x4;
typedef __attribute__((ext_vector_type(2))) unsigned u32x2;

#define NB 8
#define C1 256
#define HH 192
#define WW 192
#define GH 48
#define GW 48
#define NP 2304
#define KSEL 576
#define RH 64
#define HID 128
#define C4 1024
#define HW (HH*WW)

// ---- workspace layout (byte offsets) ----
#define WS_FLAG 0
#define WS_F 64
#define WS_W16 81280ull
#define WS_POOLED 605696ull
#define WS_PSCALE WS_POOLED
#define WS_SCORES 19480064ull

// ---- float-index offsets inside F section ----
#define F_RW1 0
#define F_RG1 16384
#define F_RB1 16448
#define F_RW2 16512
#define F_RBIAS2 16576
#define F_EG1 16580
#define F_EB1 16708
#define F_DWW 16836
#define F_DWG 17988
#define F_DWB 18116
#define F_EG2 18244
#define F_EB2 19268

__device__ __forceinline__ float b2f(unsigned short h) {
  return __uint_as_float(((unsigned)h) << 16);
}
__device__ __forceinline__ unsigned short f2b(float f) {
  unsigned u = __float_as_uint(f);
  u += 0x7FFF + ((u >> 16) & 1u);
  return (unsigned short)(u >> 16);
}
__device__ __forceinline__ unsigned pkbf(float a, float b) {
  unsigned r;
  asm("v_cvt_pk_bf16_f32 %0, %1, %2" : "=v"(r) : "v"(a), "v"(b));
  return r;
}
__device__ __forceinline__ float siluf(float v) { return v / (1.f + expf(-v)); }

// ---- dtype detector ----
__global__ void k_detect(const unsigned short* xb, char* ws) {
  __shared__ int cnt[256];
  int t = threadIdx.x;
  int c = 0;
#pragma unroll
  for (int s = 0; s < 8; ++s) {
    unsigned short u = xb[(size_t)(t * 8 + s) * 1024];
    int e = (u >> 7) & 0xFF;
    c += (u == 0 || (e >= 90 && e <= 145)) ? 1 : 0;
  }
  cnt[t] = c;
  __syncthreads();
  for (int s = 128; s > 0; s >>= 1) {
    if (t < s) cnt[t] += cnt[t + s];
    __syncthreads();
  }
  if (t == 0) *(int*)(ws + WS_FLAG) = (cnt[0] >= 1229) ? 1 : 0;
}

// ---- weight prep ----
__global__ void k_prep(const void* rw1, const void* rg1, const void* rb1, const void* rw2,
                       const void* rbias2, const void* ew1, const void* eg1, const void* eb1,
                       const void* dww, const void* dwg, const void* dwb, const void* ew2,
                       const void* eg2, const void* eb2, char* ws) {
  int bf = *(const int*)(ws + WS_FLAG);
  float* F = (float*)(ws + WS_F);
  unsigned short* W16 = (unsigned short*)(ws + WS_W16);
  int i = blockIdx.x * 256 + threadIdx.x;
  if (i >= 282433) return;
  if (i < 20289) {
    const void* src; int si; int dof;
    if      (i < 16384) { src = rw1;    si = i;          dof = F_RW1 + si; }
    else if (i < 16448) { src = rg1;    si = i - 16384;  dof = F_RG1 + si; }
    else if (i < 16512) { src = rb1;    si = i - 16448;  dof = F_RB1 + si; }
    else if (i < 16576) { src = rw2;    si = i - 16512;  dof = F_RW2 + si; }
    else if (i < 16577) { src = rbias2; si = i - 16576;  dof = F_RBIAS2 + si; }
    else if (i < 16705) { src = eg1;    si = i - 16577;  dof = F_EG1 + si; }
    else if (i < 16833) { src = eb1;    si = i - 16705;  dof = F_EB1 + si; }
    else if (i < 17985) { src = dww;    si = i - 16833;  dof = F_DWW + si; }
    else if (i < 18113) { src = dwg;    si = i - 17985;  dof = F_DWG + si; }
    else if (i < 18241) { src = dwb;    si = i - 18113;  dof = F_DWB + si; }
    else if (i < 19265) { src = eg2;    si = i - 18241;  dof = F_EG2 + si; }
    else                { src = eb2;    si = i - 19265;  dof = F_EB2 + si; }
    F[dof] = bf ? b2f(((const unsigned short*)src)[si]) : ((const float*)src)[si];
  } else {
    int j = i - 20289;
    const void* src; int si; int dof;
    if (j < 131072) { src = ew1; si = j;          dof = j; }
    else            { src = ew2; si = j - 131072; dof = j; }
    W16[dof] = bf ? ((const unsigned short*)src)[si]
                  : f2b(((const float*)src)[si]);
  }
}

// ---- 4x4 avg pool (order-preserving -> identical selection) ----
__global__ void k_pool(const void* xin, char* ws) {
  const int bf = *(const int*)(ws + WS_FLAG);
  float* pooled = (float*)(ws + WS_POOLED);
  int tid = blockIdx.x * 256 + threadIdx.x;
  int px = tid % GW;
  int t2 = tid / GW;
  int py = t2 % GH;
  int bc = t2 / GH;
  size_t base = (size_t)bc * HW + (size_t)(py * 4) * WW + px * 4;
  float s = 0.f;
  if (bf) {
#pragma unroll
    for (int r = 0; r < 4; ++r) {
      const ushort4 v = *(const ushort4*)((const unsigned short*)xin + base + r * WW);
      s += b2f(v.x) + b2f(v.y) + b2f(v.z) + b2f(v.w);
    }
  } else {
#pragma unroll
    for (int r = 0; r < 4; ++r) {
      const float4 v = *(const float4*)((const float*)xin + base + r * WW);
      s += v.x + v.y + v.z + v.w;
    }
  }
  pooled[tid] = s * 0.0625f;
}

// ---- router MLP (unchanged, proven) ----
__global__ __launch_bounds__(512, 2) void k_mlp(char* ws) {
  const float* F = (const float*)(ws + WS_F);
  const float* pooled = (const float*)(ws + WS_POOLED);
  float* scores = (float*)(ws + WS_SCORES);
  __shared__ float LP[256][68];
  __shared__ float LR[8 * 64];
  const int t = threadIdx.x;
  const int b = blockIdx.x / 36;
  const int pos0 = (blockIdx.x % 36) * 64;
  {
    const int pc = t & 15, c0 = t >> 4;
    const float* src = pooled + (size_t)(b * C1) * NP + pos0 + pc * 4;
#pragma unroll
    for (int s = 0; s < 8; ++s) {
      int c = c0 + 32 * s;
      float4 v = *(const float4*)(src + (size_t)c * NP);
      *(float4*)&LP[c][pc * 4] = v;
    }
  }
  __syncthreads();
  const int lane = t & 63;
  const int q = __builtin_amdgcn_readfirstlane(t >> 6);
  const float* wq = F + F_RW1 + q * 8 * C1;
  float acc[8];
#pragma unroll
  for (int j = 0; j < 8; ++j) acc[j] = 0.f;
  for (int c = 0; c < 256; c += 4) {
    float p0 = LP[c + 0][lane];
    float p1 = LP[c + 1][lane];
    float p2 = LP[c + 2][lane];
    float p3 = LP[c + 3][lane];
#pragma unroll
    for (int j = 0; j < 8; ++j) {
      acc[j] += wq[j * C1 + c + 0] * p0;
      acc[j] += wq[j * C1 + c + 1] * p1;
      acc[j] += wq[j * C1 + c + 2] * p2;
      acc[j] += wq[j * C1 + c + 3] * p3;
    }
  }
  const float BNS = 1.f / sqrtf(1.f + 1e-5f);
  float lp = 0.f;
#pragma unroll
  for (int j = 0; j < 8; ++j) {
    int h = q * 8 + j;
    float v = acc[j] * (F[F_RG1 + h] * BNS) + F[F_RB1 + h];
    lp += F[F_RW2 + h] * siluf(v);
  }
  LR[q * 64 + lane] = lp;
  __syncthreads();
  if (t < 64) {
    float s = F[F_RBIAS2];
#pragma unroll
    for (int j = 0; j < 8; ++j) s += LR[j * 64 + t];
    scores[b * NP + pos0 + t] = 1.f / (1.f + expf(-s));
  }
}

// ---- per-patch scale ----
__global__ void k_route(char* ws) {
  const float* scores = (const float*)(ws + WS_SCORES);
  float* pscale = (float*)(ws + WS_PSCALE);
  int b = blockIdx.x / 9, r = blockIdx.x % 9;
  __shared__ float s[NP];
  for (int i = threadIdx.x; i < NP; i += 256) s[i] = scores[b * NP + i];
  __syncthreads();
  int i = r * 256 + threadIdx.x;
  float si = s[i];
  int rank = 0;
  for (int j = 0; j < NP; ++j) {
    float sj = s[j];
    rank += (sj > si || (sj == si && j < i)) ? 1 : 0;
  }
  pscale[b * NP + i] = (rank < KSEL) ? si : 0.f;
}

// ======================= dense expert, N=64, weights direct from L2 =======================
// n = pix*16 + patch (pix = pr*2+pc within 2x2, patch = 0..15)

#define MM(A_, B_, C_) C_ = __builtin_amdgcn_mfma_f32_16x16x32_bf16(A_, B_, C_, 0, 0, 0)

#define XLOAD(P_, cc_) do { \
    if (sel) { \
      size_t o_ = (size_t)(cc_) * 16 * HW; \
      if (BF) { *(ushort4*)&P_##f0 = *(const ushort4*)(xh + xoff0 + o_); \
                *(ushort4*)&P_##f1 = *(const ushort4*)(xh + xoff1 + o_); } \
      else    { P_##f0 = *(const float4*)(xf + xoff0 + o_); \
                P_##f1 = *(const float4*)(xf + xoff1 + o_); } \
    } \
  } while(0)

#define XWRITE(P_, UT_) do { \
    unsigned lo0_, hi0_, lo1_, hi1_; \
    if (BF) { \
      ushort4 u0_ = *(ushort4*)&P_##f0, u1_ = *(ushort4*)&P_##f1; \
      lo0_ = u0_.x | ((unsigned)u0_.y << 16); hi0_ = u0_.z | ((unsigned)u0_.w << 16); \
      lo1_ = u1_.x | ((unsigned)u1_.y << 16); hi1_ = u1_.z | ((unsigned)u1_.w << 16); \
    } else { \
      lo0_ = pkbf(P_##f0.x, P_##f0.y); hi0_ = pkbf(P_##f0.z, P_##f0.w); \
      lo1_ = pkbf(P_##f1.x, P_##f1.y); hi1_ = pkbf(P_##f1.z, P_##f1.w); \
    } \
    *(unsigned*)&UT_[n_lo72 + kb0] = lo0_; \
    *(unsigned*)&UT_[n_hi72 + kb0] = hi0_; \
    *(unsigned*)&UT_[n_lo72 + kb1] = lo1_; \
    *(unsigned*)&UT_[n_hi72 + kb1] = hi1_; \
  } while(0)

// GEMM1 MFMA: A-fragments read DIRECTLY from W1 (L1/L2-resident, no LDS staging)
#define G1_MFMA(UT_, cc_) do { \
    const unsigned short* wp_ = w1base + (cc_) * 64; \
    bf16x8 b0_ = *(const bf16x8*)&UT_[ut_off]; \
    bf16x8 b1_ = *(const bf16x8*)&UT_[ut_off + 32]; \
    bf16x8 a0_ = *(const bf16x8*)(wp_); \
    bf16x8 a1_ = *(const bf16x8*)(wp_ + 16384); \
    bf16x8 a2_ = *(const bf16x8*)(wp_ + 32768); \
    bf16x8 a3_ = *(const bf16x8*)(wp_ + 49152); \
    MM(a0_, b0_, acc10); MM(a1_, b0_, acc11); MM(a2_, b0_, acc12); MM(a3_, b0_, acc13); \
    a0_ = *(const bf16x8*)(wp_ + 32); \
    a1_ = *(const bf16x8*)(wp_ + 16384 + 32); \
    a2_ = *(const bf16x8*)(wp_ + 32768 + 32); \
    a3_ = *(const bf16x8*)(wp_ + 49152 + 32); \
    MM(a0_, b1_, acc10); MM(a1_, b1_, acc11); MM(a2_, b1_, acc12); MM(a3_, b1_, acc13); \
  } while(0)

#define G1EPI(ACC_, mi_) do { \
    const int h0_ = 64 * wm + 16 * (mi_) + l4 * 4; \
    float g0_ = F[F_EG1 + h0_] * BNS,     c0_ = F[F_EB1 + h0_]; \
    float g1_ = F[F_EG1 + h0_ + 1] * BNS, c1_ = F[F_EB1 + h0_ + 1]; \
    float g2_ = F[F_EG1 + h0_ + 2] * BNS, c2_ = F[F_EB1 + h0_ + 2]; \
    float g3_ = F[F_EG1 + h0_ + 3] * BNS, c3_ = F[F_EB1 + h0_ + 3]; \
    unsigned lo_ = pkbf(siluf(ACC_[0] * g0_ + c0_), siluf(ACC_[1] * g1_ + c1_)); \
    unsigned hi_ = pkbf(siluf(ACC_[2] * g2_ + c2_), siluf(ACC_[3] * g3_ + c3_)); \
    *(u32x2*)&O1b[(16 * wn + l15) * 136 + h0_] = (u32x2){lo_, hi_}; \
  } while(0)

// GEMM2 tile: W2 A-frags direct from L2; 2 barriers/tile
#define G2_STEP(mt_) do { \
    const unsigned short* wp_ = W2b + (size_t)((mt_) * 64 + 32 * wm + l15) * 128 + l4 * 8; \
    f32x4 a20 = (f32x4){0.f, 0.f, 0.f, 0.f}; \
    f32x4 a21 = (f32x4){0.f, 0.f, 0.f, 0.f}; \
    bf16x8 a0_, a1_; \
    a0_ = *(const bf16x8*)(wp_);            a1_ = *(const bf16x8*)(wp_ + 2048); \
    MM(a0_, bq0, a20); MM(a1_, bq0, a21); \
    a0_ = *(const bf16x8*)(wp_ + 32);       a1_ = *(const bf16x8*)(wp_ + 2048 + 32); \
    MM(a0_, bq1, a20); MM(a1_, bq1, a21); \
    a0_ = *(const bf16x8*)(wp_ + 64);       a1_ = *(const bf16x8*)(wp_ + 2048 + 64); \
    MM(a0_, bq2, a20); MM(a1_, bq2, a21); \
    a0_ = *(const bf16x8*)(wp_ + 96);       a1_ = *(const bf16x8*)(wp_ + 2048 + 96); \
    MM(a0_, bq3, a20); MM(a1_, bq3, a21); \
    _Pragma("unroll") \
    for (int r_ = 0; r_ < 4; ++r_) { \
      int ml0_ = 32 * wm + l4 * 4 + r_; \
      int m20_ = (mt_) * 64 + ml0_; \
      OT[ml0_ * 68 + otc] = a20[r_] * (F[F_EG2 + m20_] * BNS) + F[F_EB2 + m20_]; \
      OT[(ml0_ + 16) * 68 + otc] = a21[r_] * (F[F_EG2 + m20_ + 16] * BNS) + F[F_EB2 + m20_ + 16]; \
    } \
    __syncthreads(); \
    _Pragma("unroll") \
    for (int s_ = 0; s_ < 2; ++s_) { \
      int cl_ = o_cl + 8 * s_; \
      int ch_ = (mt_) * 16 + cl_; \
      size_t ob_ = ((size_t)(bC1 + ch_) * HH + r0 + o_rr) * WW + c0 + o_p * 4; \
      int rb_ = (4 * cl_ + 2 * (o_rr & 1)) * 68 + (o_rr >> 1) * 32 + o_p; \
      float e0_ = OT[rb_] * ps; \
      float e1_ = OT[rb_ + 68] * ps; \
      float e2_ = OT[rb_ + 16] * ps; \
      float e3_ = OT[rb_ + 68 + 16] * ps; \
      if (BF) { ushort4 o4_ = {f2b(e0_), f2b(e1_), f2b(e2_), f2b(e3_)}; \
                *(ushort4*)((unsigned short*)outv + ob_) = o4_; } \
      else    { float4 o4_ = {e0_, e1_, e2_, e3_}; \
                *(float4*)((float*)outv + ob_) = o4_; } \
    } \
    __syncthreads(); \
  } while(0)

__global__ __launch_bounds__(512, 6) void k_expert(const void* xin, void* outv, char* ws) {
  const int BF = *(const int*)(ws + WS_FLAG);
  const float* F = (const float*)(ws + WS_F);
  const unsigned short* W1b = (const unsigned short*)(ws + WS_W16);
  const unsigned short* W2b = W1b + 131072;
  const float* pscale = (const float*)(ws + WS_PSCALE);

  // LDS (34,880 B -> >=3, up to 4 blocks/CU):
  // GEMM1: UT0@0, UT1@9216 (2x9216)
  // epi:   O1b bf16 [64n][136h] @0 (17408, aliases UT)
  // dw:    Y2T bf16 [64n][136h] @17408 (17408)
  // GEMM2: OT fp32 [64m][68n] @0 (17408, aliases O1b) + Y2T live
  __shared__ __align__(16) char LB[34880];
  unsigned short* UT0 = (unsigned short*)(LB);
  unsigned short* UT1 = (unsigned short*)(LB + 9216);
  unsigned short* O1b = (unsigned short*)(LB);
  unsigned short* Y2T = (unsigned short*)(LB + 17408);
  float*          OT  = (float*)(LB);
  float*          PSs = (float*)(LB + 34816);

  const int t = threadIdx.x;
  const int lane = t & 63;
  const int w = t >> 6;
  const int wm = w >> 2, wn = w & 3;
  const int l15 = lane & 15, l4 = lane >> 4;
  const int bid = blockIdx.x;
  const int xq = bid % 3;
  const int py = (bid / 3) % GH;
  const int b  = bid / (3 * GH);
  const int r0 = py * 4, c0 = xq * 64;
  const int bC1 = b * C1;
  const float BNS = 1.f / sqrtf(1.f + 1e-5f);

  if (t < 16) PSs[t] = pscale[b * NP + py * GW + xq * 16 + t];
  __syncthreads();
  const float ps = PSs[t & 15];
  const bool sel = ps != 0.f;

  // staging coords
  const int rr = (t >> 4) & 3, v4 = t & 15;
  const int n_lo72 = (32 * (rr >> 1) + v4) * 72;
  const int n_hi72 = n_lo72 + 16 * 72;
  const int kb0 = 4 * w + 2 * (rr & 1);
  const int kb1 = kb0 + 32;
  const size_t xoff0 = ((size_t)bC1 + w) * HW + (size_t)(r0 + rr) * WW + c0 + v4 * 4;
  const size_t xoff1 = xoff0 + (size_t)8 * HW;
  // mfma coords
  const int ut_off = (16 * wn + l15) * 72 + l4 * 8;
  const unsigned short* w1base = W1b + (size_t)(64 * wm + l15) * 1024 + l4 * 8;
  const int otc = 16 * wn + l15;
  // store coords
  const int o_p = t & 15, o_rr = (t >> 4) & 3, o_cl = t >> 6;

  const float* xf = (const float*)xin;
  const unsigned short* xh = (const unsigned short*)xin;

  // named staging registers (zero-init; unselected lanes keep zeros)
  float4 Af0 = {0,0,0,0}, Af1 = {0,0,0,0}, Bf0 = {0,0,0,0}, Bf1 = {0,0,0,0};

  f32x4 acc10 = (f32x4){0.f,0.f,0.f,0.f};
  f32x4 acc11 = (f32x4){0.f,0.f,0.f,0.f};
  f32x4 acc12 = (f32x4){0.f,0.f,0.f,0.f};
  f32x4 acc13 = (f32x4){0.f,0.f,0.f,0.f};

  // ---- GEMM1: 16 K-chunks, LDS double-buffered (x only in LDS path) ----
  XLOAD(A, 0);
  XLOAD(B, 1);
  for (int cc2 = 0; cc2 < 8; ++cc2) {
    int cc = cc2 * 2;
    XWRITE(A, UT0);
    if (cc2 < 7) XLOAD(A, cc + 2);
    __syncthreads();
    G1_MFMA(UT0, cc);
    XWRITE(B, UT1);
    if (cc2 < 7) XLOAD(B, cc + 3);
    __syncthreads();
    G1_MFMA(UT1, cc + 1);
  }

  __syncthreads();               // all GEMM1 LDS reads done (O1b aliases UT)
  G1EPI(acc10, 0);
  G1EPI(acc11, 1);
  G1EPI(acc12, 2);
  G1EPI(acc13, 3);
  __syncthreads();

  // ---- depthwise 3x3 on 2x2 + BN + SiLU: O1b -> Y2T (both [n][136h] bf16) ----
  {
    const int dh = t & 127;
    const int dgrp = t >> 7;
    const float* kw = F + F_DWW + dh * 9;
    float k0 = kw[0], k1 = kw[1], k2 = kw[2], k3 = kw[3], k4 = kw[4];
    float k5 = kw[5], k6 = kw[6], k7 = kw[7], k8 = kw[8];
    float sd = F[F_DWG + dh] * BNS, bd = F[F_DWB + dh];
#pragma unroll
    for (int s = 0; s < 4; ++s) {
      int patch = dgrp * 4 + s;
      int nb = patch * 136 + dh;
      float i0 = b2f(O1b[nb]);
      float i1 = b2f(O1b[nb + 2176]);
      float i2 = b2f(O1b[nb + 4352]);
      float i3 = b2f(O1b[nb + 6528]);
      float o00 = k4 * i0 + k5 * i1 + k7 * i2 + k8 * i3;
      float o01 = k3 * i0 + k4 * i1 + k6 * i2 + k7 * i3;
      float o10 = k1 * i0 + k2 * i1 + k4 * i2 + k5 * i3;
      float o11 = k0 * i0 + k1 * i1 + k3 * i2 + k4 * i3;
      Y2T[nb] = f2b(siluf(o00 * sd + bd));
      Y2T[nb + 2176] = f2b(siluf(o01 * sd + bd));
      Y2T[nb + 4352] = f2b(siluf(o10 * sd + bd));
      Y2T[nb + 6528] = f2b(siluf(o11 * sd + bd));
    }
  }
  __syncthreads();

  // ---- GEMM2: 16 M-tiles of 64; W2 a-frags direct from L2; 2 barriers/tile ----
  const int ybase = (16 * wn + l15) * 136 + l4 * 8;
  bf16x8 bq0 = *(const bf16x8*)&Y2T[ybase];
  bf16x8 bq1 = *(const bf16x8*)&Y2T[ybase + 32];
  bf16x8 bq2 = *(const bf16x8*)&Y2T[ybase + 64];
  bf16x8 bq3 = *(const bf16x8*)&Y2T[ybase + 96];

  for (int mt = 0; mt < 16; ++mt) {
    G2_STEP(mt);
  }
}

extern "C" void kernel_launch(void* const* d_in, const int* in_sizes, int n_in,
                              void* d_out, int out_size, void* d_ws, size_t ws_size,
                              hipStream_t stream) {
  char* ws = (char*)d_ws;
  const void* x = d_in[0];
  k_detect<<<1, 256, 0, stream>>>((const unsigned short*)x, ws);
  k_prep<<<1104, 256, 0, stream>>>(d_in[1], d_in[2], d_in[3], d_in[4], d_in[5], d_in[6],
                                   d_in[7], d_in[8], d_in[9], d_in[10], d_in[11], d_in[12],
                                   d_in[13], d_in[14], ws);
  k_pool<<<18432, 256, 0, stream>>>(x, ws);
  k_mlp<<<288, 512, 0, stream>>>(ws);
  k_route<<<72, 256, 0, stream>>>(ws);
  k_expert<<<1152, 512, 0, stream>>>(x, d_out, ws);
}